// Round 4
// baseline (33940.796 us; speedup 1.0000x reference)
//
#include <hip/hip_runtime.h>
#include <hip/hip_bf16.h>

#define TSEQ 65536
#define INPUT_SIZE 128
#define HIDDEN 100
#define GATES 400   // 4*HIDDEN

typedef __attribute__((ext_vector_type(8))) short bf16x8;
typedef __attribute__((ext_vector_type(4))) float f32x4;

__device__ __forceinline__ unsigned short f2bf(float x) {
    union { float f; unsigned int u; } v; v.f = x;
    unsigned int r = v.u + 0x7fffu + ((v.u >> 16) & 1u);
    return (unsigned short)(r >> 16);
}
__device__ __forceinline__ float bf2f(unsigned int u) {
    union { unsigned int u; float f; } v; v.u = u << 16; return v.f;
}
__device__ __forceinline__ float rcp_fast(float x) { return __builtin_amdgcn_rcpf(x); }
__device__ __forceinline__ float sigm(float x) { return rcp_fast(1.0f + __expf(-x)); }
__device__ __forceinline__ float tanh_fast(float x) {
    return 1.0f - 2.0f * rcp_fast(__expf(2.0f * x) + 1.0f);
}

// barrier without vmcnt drain: LDS-drain + s_barrier + compiler memory fence
#define LDS_BARRIER()                                              \
    do {                                                           \
        asm volatile("s_waitcnt lgkmcnt(0)" ::: "memory");         \
        __builtin_amdgcn_s_barrier();                              \
        asm volatile("" ::: "memory");                             \
    } while (0)

// ---------------------------------------------------------------------------
// Kernel 1: xp_perm[t][4*u + g] = b_ih[j] + b_hh[j] + sum_k x[t][k]*W_ih[j][k]
// where j = g*100 + u. Unit-major/gate-minor layout.
// ---------------------------------------------------------------------------
__global__ __launch_bounds__(256) void xproj_kernel(
    const float* __restrict__ x,     // [TSEQ][128]
    const float* __restrict__ W,     // [400][128]
    const float* __restrict__ bi,    // [400]
    const float* __restrict__ bh,    // [400]
    float* __restrict__ xp)          // [TSEQ][400] (permuted)
{
    __shared__ __align__(16) float xs[16 * 128];
    const int tid = threadIdx.x;
    const int t0 = blockIdx.x * 16;

#pragma unroll
    for (int i = 0; i < 8; ++i)
        xs[i * 256 + tid] = x[(size_t)t0 * 128 + i * 256 + tid];
    __syncthreads();

    const int j1 = tid;
    const int j2 = tid + 256;
    const bool has2 = (j2 < GATES);
    const int p1 = 4 * (j1 % 100) + (j1 / 100);
    const int p2 = has2 ? (4 * (j2 % 100) + (j2 / 100)) : 0;

    float acc1[16], acc2[16];
    const float bias1 = bi[j1] + bh[j1];
    const float bias2 = has2 ? (bi[j2] + bh[j2]) : 0.0f;
#pragma unroll
    for (int tt = 0; tt < 16; ++tt) { acc1[tt] = bias1; acc2[tt] = bias2; }

    const float4* W4 = reinterpret_cast<const float4*>(W);
    const float4* xs4 = reinterpret_cast<const float4*>(xs);

    for (int kk = 0; kk < 32; ++kk) {
        const float4 wa = W4[(size_t)j1 * 32 + kk];
        float4 wb = make_float4(0.f, 0.f, 0.f, 0.f);
        if (has2) wb = W4[(size_t)j2 * 32 + kk];
#pragma unroll
        for (int tt = 0; tt < 16; ++tt) {
            const float4 xv = xs4[tt * 32 + kk];
            acc1[tt] = fmaf(wa.x, xv.x, acc1[tt]);
            acc1[tt] = fmaf(wa.y, xv.y, acc1[tt]);
            acc1[tt] = fmaf(wa.z, xv.z, acc1[tt]);
            acc1[tt] = fmaf(wa.w, xv.w, acc1[tt]);
            acc2[tt] = fmaf(wb.x, xv.x, acc2[tt]);
            acc2[tt] = fmaf(wb.y, xv.y, acc2[tt]);
            acc2[tt] = fmaf(wb.z, xv.z, acc2[tt]);
            acc2[tt] = fmaf(wb.w, xv.w, acc2[tt]);
        }
    }

#pragma unroll
    for (int tt = 0; tt < 16; ++tt) {
        xp[(size_t)(t0 + tt) * GATES + p1] = acc1[tt];
        if (has2) xp[(size_t)(t0 + tt) * GATES + p2] = acc2[tt];
    }
}

// ---------------------------------------------------------------------------
// Kernel 2: LSTM recurrence, one block, 512 threads (8 waves), 1 barrier/step,
// ZERO preact LDS traffic.
// Wave w owns tiles 3w..3w+2 (w7 also tile 24). Since B cols are replicated h,
// D of tile ti gives EVERY lane in row-group q=lane>>4 the full 4-gate preact
// of unit 4*ti+q in its 4 acc regs. Lane (q, m) selects slot m (cndmask chain)
// and does the cell update for unit 12w+4m+q entirely in registers; only the
// 2-byte bf16 h goes through LDS (write -> barrier -> b-frag read).
// NOTE: no __restrict__ -> hs stores alias-block W_hh load rematerialization.
// ---------------------------------------------------------------------------
__global__ __launch_bounds__(512, 1) void lstm_rec_kernel(
    const float* xp,         // [TSEQ][400] permuted, includes biases
    const float* Whh,        // [400][100] original layout
    unsigned short* hs)      // [TSEQ][100] bf16
{
    __shared__ __align__(16) unsigned short h_lds[2][128];  // bf16 h, zero-padded

    const int tid = threadIdx.x;
    const int lane = tid & 63;
    const int w = tid >> 6;          // wave 0..7
    const int bq = lane >> 4;        // k-group AND D row-group q (0..3)
    const int m = lane & 15;         // A row within tile / D col

    // ---- A fragments: 4 tile-slots (wave w: tiles 3w..3w+2; slot 3 = tile 24, w7 only)
    bf16x8 afrag[4][4];
#pragma unroll
    for (int i = 0; i < 4; ++i) {
        const int ti = (i < 3) ? (3 * w + i) : 24;
        const bool valid = (i < 3) || (w == 7);
        const int g = m & 3;                  // permuted tile-row -> gate
        const int uu = 4 * ti + (m >> 2);     // -> hidden unit
        const int orow = g * 100 + uu;        // original W_hh row
#pragma unroll
        for (int kk = 0; kk < 4; ++kk) {
            float vals[8];
            if (valid && kk < 3) {
                const float4 w0 = *(const float4*)&Whh[(size_t)orow * 100 + kk * 32 + bq * 8];
                const float4 w1 = *(const float4*)&Whh[(size_t)orow * 100 + kk * 32 + bq * 8 + 4];
                vals[0] = w0.x; vals[1] = w0.y; vals[2] = w0.z; vals[3] = w0.w;
                vals[4] = w1.x; vals[5] = w1.y; vals[6] = w1.z; vals[7] = w1.w;
            } else if (valid && bq == 0) {    // kk==3: k=96..103, only 96..99 real
                const float4 w0 = *(const float4*)&Whh[(size_t)orow * 100 + 96];
                vals[0] = w0.x; vals[1] = w0.y; vals[2] = w0.z; vals[3] = w0.w;
                vals[4] = 0.f; vals[5] = 0.f; vals[6] = 0.f; vals[7] = 0.f;
            } else {
#pragma unroll
                for (int j = 0; j < 8; ++j) vals[j] = 0.f;
            }
#pragma unroll
            for (int j = 0; j < 8; ++j) afrag[i][kk][j] = (short)f2bf(vals[j]);
        }
    }

    // ---- cell-lane mapping: lane (q=bq, m) handles unit 4*tile(slot m)+q
    const bool cell = (m < 3) || (w == 7 && m == 3);
    const int unit = 12 * w + 4 * m + bq;     // valid when `cell` (<100)

    // ---- init
    if (tid < 128) { h_lds[0][tid] = 0; h_lds[1][tid] = 0; }
    float c = 0.0f;
    float4 xpv[4];
    if (cell) {
#pragma unroll
        for (int p = 0; p < 4; ++p)
            xpv[p] = *(const float4*)&xp[(size_t)p * GATES + 4 * unit];
    }
    __syncthreads();

    for (int t = 0; t < TSEQ; t += 4) {
#pragma unroll
        for (int u = 0; u < 4; ++u) {
            const int tt = t + u;
            const int cur = u & 1;           // parity of tt == parity of u

            // ---- B fragments: h broadcast, 16B LDS reads (conflict-free)
            bf16x8 bfr[4];
#pragma unroll
            for (int kk = 0; kk < 4; ++kk) {
                const uint4 braw = *(const uint4*)&h_lds[cur][kk * 32 + bq * 8];
                bfr[kk] = __builtin_bit_cast(bf16x8, braw);
            }

            // ---- MFMA: per tile two 2-chains + one add (shorter dep chain)
            f32x4 pa_s[4];
#pragma unroll
            for (int i = 0; i < 4; ++i) {
                if (i < 3 || w == 7) {
                    f32x4 e = {0.f, 0.f, 0.f, 0.f};
                    f32x4 o = {0.f, 0.f, 0.f, 0.f};
                    e = __builtin_amdgcn_mfma_f32_16x16x32_bf16(afrag[i][0], bfr[0], e, 0, 0, 0);
                    o = __builtin_amdgcn_mfma_f32_16x16x32_bf16(afrag[i][1], bfr[1], o, 0, 0, 0);
                    e = __builtin_amdgcn_mfma_f32_16x16x32_bf16(afrag[i][2], bfr[2], e, 0, 0, 0);
                    o = __builtin_amdgcn_mfma_f32_16x16x32_bf16(afrag[i][3], bfr[3], o, 0, 0, 0);
                    pa_s[i] = e + o;
                } else {
                    pa_s[i] = (f32x4){0.f, 0.f, 0.f, 0.f};
                }
            }

            // ---- slot select (all-register, static indices) + cell update
            f32x4 pa = pa_s[0];
            pa = (m == 1) ? pa_s[1] : pa;
            pa = (m == 2) ? pa_s[2] : pa;
            if (w == 7) pa = (m == 3) ? pa_s[3] : pa;

            if (cell) {
                const float4 xq = xpv[u];
                const float gi = sigm(pa.x + xq.x);
                const float gf = sigm(pa.y + xq.y);
                const float gg = tanh_fast(pa.z + xq.z);
                const float go = sigm(pa.w + xq.w);
                c = fmaf(gf, c, gi * gg);
                const float hv = go * tanh_fast(c);
                const unsigned short hb = f2bf(hv);
                h_lds[1 - cur][unit] = hb;                     // publish
                hs[(size_t)tt * HIDDEN + unit] = hb;           // fire-and-forget bf16
                if (tt + 4 < TSEQ)                             // depth-4 prefetch
                    xpv[u] = *(const float4*)&xp[(size_t)(tt + 4) * GATES + 4 * unit];
            }
            LDS_BARRIER();   // h visible to all waves for step tt+1
        }
    }
}

// ---------------------------------------------------------------------------
// Kernel 3: out[t] = sigmoid(dot(hs_bf16[t], W_lin) + b_lin)
// ---------------------------------------------------------------------------
__global__ __launch_bounds__(256) void pred_kernel(
    const unsigned short* __restrict__ hs,   // [TSEQ][100] bf16
    const float* __restrict__ wlin,          // [100]
    const float* __restrict__ blin,          // [1]
    float* __restrict__ out)                 // [TSEQ]
{
    __shared__ __align__(16) float wl[HIDDEN];
    const int tid = threadIdx.x;
    if (tid < HIDDEN) wl[tid] = wlin[tid];
    __syncthreads();

    const int t = blockIdx.x * 256 + tid;
    const unsigned short* hrow = hs + (size_t)t * HIDDEN;   // 8B-aligned
    float acc = blin[0];
#pragma unroll
    for (int kk = 0; kk < 25; ++kk) {                       // 25 x uint2 = 100 bf16
        const uint2 v = *(const uint2*)&hrow[kk * 4];
        acc = fmaf(bf2f(v.x & 0xffffu), wl[kk * 4 + 0], acc);
        acc = fmaf(bf2f(v.x >> 16),     wl[kk * 4 + 1], acc);
        acc = fmaf(bf2f(v.y & 0xffffu), wl[kk * 4 + 2], acc);
        acc = fmaf(bf2f(v.y >> 16),     wl[kk * 4 + 3], acc);
    }
    out[t] = sigm(acc);
}

// ---------------------------------------------------------------------------
extern "C" void kernel_launch(void* const* d_in, const int* in_sizes, int n_in,
                              void* d_out, int out_size, void* d_ws, size_t ws_size,
                              hipStream_t stream) {
    const float* x     = (const float*)d_in[0];  // [65536,128]
    const float* W_ih  = (const float*)d_in[1];  // [400,128]
    const float* W_hh  = (const float*)d_in[2];  // [400,100]
    const float* b_ih  = (const float*)d_in[3];  // [400]
    const float* b_hh  = (const float*)d_in[4];  // [400]
    const float* W_lin = (const float*)d_in[5];  // [1,100]
    const float* b_lin = (const float*)d_in[6];  // [1]
    float* out = (float*)d_out;                  // [65536]

    float* xp = (float*)d_ws;                                  // [TSEQ*400] fp32
    unsigned short* hs = (unsigned short*)(xp + (size_t)TSEQ * GATES);  // [TSEQ*100] bf16

    xproj_kernel<<<TSEQ / 16, 256, 0, stream>>>(x, W_ih, b_ih, b_hh, xp);
    lstm_rec_kernel<<<1, 512, 0, stream>>>(xp, W_hh, hs);
    pred_kernel<<<TSEQ / 256, 256, 0, stream>>>(hs, W_lin, b_lin, out);
}

// Round 5
// 33833.261 us; speedup vs baseline: 1.0032x; 1.0032x over previous
//
#include <hip/hip_runtime.h>
#include <hip/hip_bf16.h>

#define TSEQ 65536
#define INPUT_SIZE 128
#define HIDDEN 100
#define GATES 400   // 4*HIDDEN

typedef __attribute__((ext_vector_type(8))) short bf16x8;
typedef __attribute__((ext_vector_type(4))) float f32x4;

__device__ __forceinline__ unsigned short f2bf(float x) {
    union { float f; unsigned int u; } v; v.f = x;
    unsigned int r = v.u + 0x7fffu + ((v.u >> 16) & 1u);
    return (unsigned short)(r >> 16);
}
__device__ __forceinline__ float bf2f(unsigned int u) {
    union { unsigned int u; float f; } v; v.u = u << 16; return v.f;
}
__device__ __forceinline__ float rcp_fast(float x) { return __builtin_amdgcn_rcpf(x); }
__device__ __forceinline__ float sigm(float x) { return rcp_fast(1.0f + __expf(-x)); }
__device__ __forceinline__ float tanh_fast(float x) {
    return 1.0f - 2.0f * rcp_fast(__expf(2.0f * x) + 1.0f);
}

// Make a register value opaque to the optimizer: it is no longer a load
// result, so it cannot be rematerialized/sunk into the loop (R4 failure:
// compiler re-loaded + re-converted all W_hh fragments EVERY step).
__device__ __forceinline__ void pin(bf16x8& x) {
    asm volatile("" : "+v"(x));
}

// barrier without vmcnt drain: LDS-drain + s_barrier + compiler memory fence
#define LDS_BARRIER()                                              \
    do {                                                           \
        asm volatile("s_waitcnt lgkmcnt(0)" ::: "memory");         \
        __builtin_amdgcn_s_barrier();                              \
        asm volatile("" ::: "memory");                             \
    } while (0)

// ---------------------------------------------------------------------------
// Kernel 1: xp_perm[t][4*u + g] = b_ih[j] + b_hh[j] + sum_k x[t][k]*W_ih[j][k]
// where j = g*100 + u. Unit-major/gate-minor layout.
// ---------------------------------------------------------------------------
__global__ __launch_bounds__(256) void xproj_kernel(
    const float* __restrict__ x,     // [TSEQ][128]
    const float* __restrict__ W,     // [400][128]
    const float* __restrict__ bi,    // [400]
    const float* __restrict__ bh,    // [400]
    float* __restrict__ xp)          // [TSEQ][400] (permuted)
{
    __shared__ __align__(16) float xs[16 * 128];
    const int tid = threadIdx.x;
    const int t0 = blockIdx.x * 16;

#pragma unroll
    for (int i = 0; i < 8; ++i)
        xs[i * 256 + tid] = x[(size_t)t0 * 128 + i * 256 + tid];
    __syncthreads();

    const int j1 = tid;
    const int j2 = tid + 256;
    const bool has2 = (j2 < GATES);
    const int p1 = 4 * (j1 % 100) + (j1 / 100);
    const int p2 = has2 ? (4 * (j2 % 100) + (j2 / 100)) : 0;

    float acc1[16], acc2[16];
    const float bias1 = bi[j1] + bh[j1];
    const float bias2 = has2 ? (bi[j2] + bh[j2]) : 0.0f;
#pragma unroll
    for (int tt = 0; tt < 16; ++tt) { acc1[tt] = bias1; acc2[tt] = bias2; }

    const float4* W4 = reinterpret_cast<const float4*>(W);
    const float4* xs4 = reinterpret_cast<const float4*>(xs);

    for (int kk = 0; kk < 32; ++kk) {
        const float4 wa = W4[(size_t)j1 * 32 + kk];
        float4 wb = make_float4(0.f, 0.f, 0.f, 0.f);
        if (has2) wb = W4[(size_t)j2 * 32 + kk];
#pragma unroll
        for (int tt = 0; tt < 16; ++tt) {
            const float4 xv = xs4[tt * 32 + kk];
            acc1[tt] = fmaf(wa.x, xv.x, acc1[tt]);
            acc1[tt] = fmaf(wa.y, xv.y, acc1[tt]);
            acc1[tt] = fmaf(wa.z, xv.z, acc1[tt]);
            acc1[tt] = fmaf(wa.w, xv.w, acc1[tt]);
            acc2[tt] = fmaf(wb.x, xv.x, acc2[tt]);
            acc2[tt] = fmaf(wb.y, xv.y, acc2[tt]);
            acc2[tt] = fmaf(wb.z, xv.z, acc2[tt]);
            acc2[tt] = fmaf(wb.w, xv.w, acc2[tt]);
        }
    }

#pragma unroll
    for (int tt = 0; tt < 16; ++tt) {
        xp[(size_t)(t0 + tt) * GATES + p1] = acc1[tt];
        if (has2) xp[(size_t)(t0 + tt) * GATES + p2] = acc2[tt];
    }
}

// ---------------------------------------------------------------------------
// Kernel 2: LSTM recurrence, one block, 512 threads (8 waves), 1 barrier/step,
// zero preact LDS traffic, W_hh fragments PINNED in VGPRs.
// Wave w owns tiles 3w..3w+2 (w7 also tile 24). B cols are replicated h, so
// D of tile ti gives every lane in row-group q=lane>>4 the full 4-gate preact
// of unit 4*ti+q in its 4 acc regs. Lane (q, m) selects slot m and does the
// cell update for unit 12w+4m+q entirely in registers; only the 2-byte bf16 h
// goes through LDS (write -> barrier -> b-frag read).
// ---------------------------------------------------------------------------
__global__ __launch_bounds__(512, 2) void lstm_rec_kernel(
    const float* __restrict__ xp,    // [TSEQ][400] permuted, includes biases
    const float* __restrict__ Whh,   // [400][100] original layout
    unsigned short* __restrict__ hs) // [TSEQ][100] bf16
{
    __shared__ __align__(16) unsigned short h_lds[2][128];  // bf16 h, zero-padded

    const int tid = threadIdx.x;
    const int lane = tid & 63;
    const int w = tid >> 6;          // wave 0..7
    const int bq = lane >> 4;        // k-group AND D row-group q (0..3)
    const int m = lane & 15;         // A row within tile / D col

    // ---- A fragments: 4 tile-slots (wave w: tiles 3w..3w+2; slot 3 = tile 24, w7 only)
    bf16x8 afrag[4][4];
#pragma unroll
    for (int i = 0; i < 4; ++i) {
        const int ti = (i < 3) ? (3 * w + i) : 24;
        const bool valid = (i < 3) || (w == 7);
        const int g = m & 3;                  // permuted tile-row -> gate
        const int uu = 4 * ti + (m >> 2);     // -> hidden unit
        const int orow = g * 100 + uu;        // original W_hh row
#pragma unroll
        for (int kk = 0; kk < 4; ++kk) {
            float vals[8];
            if (valid && kk < 3) {
                const float4 w0 = *(const float4*)&Whh[(size_t)orow * 100 + kk * 32 + bq * 8];
                const float4 w1 = *(const float4*)&Whh[(size_t)orow * 100 + kk * 32 + bq * 8 + 4];
                vals[0] = w0.x; vals[1] = w0.y; vals[2] = w0.z; vals[3] = w0.w;
                vals[4] = w1.x; vals[5] = w1.y; vals[6] = w1.z; vals[7] = w1.w;
            } else if (valid && bq == 0) {    // kk==3: k=96..103, only 96..99 real
                const float4 w0 = *(const float4*)&Whh[(size_t)orow * 100 + 96];
                vals[0] = w0.x; vals[1] = w0.y; vals[2] = w0.z; vals[3] = w0.w;
                vals[4] = 0.f; vals[5] = 0.f; vals[6] = 0.f; vals[7] = 0.f;
            } else {
#pragma unroll
                for (int j = 0; j < 8; ++j) vals[j] = 0.f;
            }
#pragma unroll
            for (int j = 0; j < 8; ++j) afrag[i][kk][j] = (short)f2bf(vals[j]);
            pin(afrag[i][kk]);   // CRITICAL: forbid remat/sink of the weight regs
        }
    }

    // ---- cell-lane mapping: lane (q=bq, m) handles unit 4*tile(slot m)+q
    const bool cell = (m < 3) || (w == 7 && m == 3);
    const int unit = 12 * w + 4 * m + bq;     // valid when `cell` (<100)

    // ---- init
    if (tid < 128) { h_lds[0][tid] = 0; h_lds[1][tid] = 0; }
    float c = 0.0f;
    float4 xpv[4];
    if (cell) {
#pragma unroll
        for (int p = 0; p < 4; ++p)
            xpv[p] = *(const float4*)&xp[(size_t)p * GATES + 4 * unit];
    }
    __syncthreads();

    for (int t = 0; t < TSEQ; t += 4) {
#pragma unroll
        for (int u = 0; u < 4; ++u) {
            const int tt = t + u;
            const int cur = u & 1;           // parity of tt == parity of u

            // ---- B fragments: h broadcast, 16B LDS reads (conflict-free)
            bf16x8 bfr[4];
#pragma unroll
            for (int kk = 0; kk < 4; ++kk) {
                const uint4 braw = *(const uint4*)&h_lds[cur][kk * 32 + bq * 8];
                bfr[kk] = __builtin_bit_cast(bf16x8, braw);
            }

            // ---- MFMA: per tile two 2-chains + one add (shorter dep chain)
            f32x4 pa_s[4];
#pragma unroll
            for (int i = 0; i < 4; ++i) {
                if (i < 3 || w == 7) {
                    f32x4 e = {0.f, 0.f, 0.f, 0.f};
                    f32x4 o = {0.f, 0.f, 0.f, 0.f};
                    e = __builtin_amdgcn_mfma_f32_16x16x32_bf16(afrag[i][0], bfr[0], e, 0, 0, 0);
                    o = __builtin_amdgcn_mfma_f32_16x16x32_bf16(afrag[i][1], bfr[1], o, 0, 0, 0);
                    e = __builtin_amdgcn_mfma_f32_16x16x32_bf16(afrag[i][2], bfr[2], e, 0, 0, 0);
                    o = __builtin_amdgcn_mfma_f32_16x16x32_bf16(afrag[i][3], bfr[3], o, 0, 0, 0);
                    pa_s[i] = e + o;
                } else {
                    pa_s[i] = (f32x4){0.f, 0.f, 0.f, 0.f};
                }
            }

            // ---- slot select (all-register, static indices) + cell update
            f32x4 pa = pa_s[0];
            pa = (m == 1) ? pa_s[1] : pa;
            pa = (m == 2) ? pa_s[2] : pa;
            if (w == 7) pa = (m == 3) ? pa_s[3] : pa;

            if (cell) {
                const float4 xq = xpv[u];
                const float gi = sigm(pa.x + xq.x);
                const float gf = sigm(pa.y + xq.y);
                const float gg = tanh_fast(pa.z + xq.z);
                const float go = sigm(pa.w + xq.w);
                c = fmaf(gf, c, gi * gg);
                const float hv = go * tanh_fast(c);
                const unsigned short hb = f2bf(hv);
                h_lds[1 - cur][unit] = hb;                     // publish
                hs[(size_t)tt * HIDDEN + unit] = hb;           // fire-and-forget bf16
                if (tt + 4 < TSEQ)                             // depth-4 prefetch
                    xpv[u] = *(const float4*)&xp[(size_t)(tt + 4) * GATES + 4 * unit];
            }
            LDS_BARRIER();   // h visible to all waves for step tt+1
        }
    }
}

// ---------------------------------------------------------------------------
// Kernel 3: out[t] = sigmoid(dot(hs_bf16[t], W_lin) + b_lin)
// ---------------------------------------------------------------------------
__global__ __launch_bounds__(256) void pred_kernel(
    const unsigned short* __restrict__ hs,   // [TSEQ][100] bf16
    const float* __restrict__ wlin,          // [100]
    const float* __restrict__ blin,          // [1]
    float* __restrict__ out)                 // [TSEQ]
{
    __shared__ __align__(16) float wl[HIDDEN];
    const int tid = threadIdx.x;
    if (tid < HIDDEN) wl[tid] = wlin[tid];
    __syncthreads();

    const int t = blockIdx.x * 256 + tid;
    const unsigned short* hrow = hs + (size_t)t * HIDDEN;   // 8B-aligned
    float acc = blin[0];
#pragma unroll
    for (int kk = 0; kk < 25; ++kk) {                       // 25 x uint2 = 100 bf16
        const uint2 v = *(const uint2*)&hrow[kk * 4];
        acc = fmaf(bf2f(v.x & 0xffffu), wl[kk * 4 + 0], acc);
        acc = fmaf(bf2f(v.x >> 16),     wl[kk * 4 + 1], acc);
        acc = fmaf(bf2f(v.y & 0xffffu), wl[kk * 4 + 2], acc);
        acc = fmaf(bf2f(v.y >> 16),     wl[kk * 4 + 3], acc);
    }
    out[t] = sigm(acc);
}

// ---------------------------------------------------------------------------
extern "C" void kernel_launch(void* const* d_in, const int* in_sizes, int n_in,
                              void* d_out, int out_size, void* d_ws, size_t ws_size,
                              hipStream_t stream) {
    const float* x     = (const float*)d_in[0];  // [65536,128]
    const float* W_ih  = (const float*)d_in[1];  // [400,128]
    const float* W_hh  = (const float*)d_in[2];  // [400,100]
    const float* b_ih  = (const float*)d_in[3];  // [400]
    const float* b_hh  = (const float*)d_in[4];  // [400]
    const float* W_lin = (const float*)d_in[5];  // [1,100]
    const float* b_lin = (const float*)d_in[6];  // [1]
    float* out = (float*)d_out;                  // [65536]

    float* xp = (float*)d_ws;                                  // [TSEQ*400] fp32
    unsigned short* hs = (unsigned short*)(xp + (size_t)TSEQ * GATES);  // [TSEQ*100] bf16

    xproj_kernel<<<TSEQ / 16, 256, 0, stream>>>(x, W_ih, b_ih, b_hh, xp);
    lstm_rec_kernel<<<1, 512, 0, stream>>>(xp, W_hh, hs);
    pred_kernel<<<TSEQ / 256, 256, 0, stream>>>(hs, W_lin, b_lin, out);
}